// Round 4
// baseline (653.296 us; speedup 1.0000x reference)
//
#include <hip/hip_runtime.h>
#include <hip/hip_bf16.h>

// ---------------------------------------------------------------------------
// GNN layer:
//   hproj   = hidden @ Ws^T                       (200000 x 64)   [rowproj64]
//   hrproj  = rela_embed @ Wr^T                   (401 x 64)      [relproj]
//   hqrproj = rela_embed[q_rel] @ Wqr^T + b       (8 x 64)        [qrproj]
//   ct[b][r][:] = hrproj[r] + hqrproj[b]          (8 x 401 x 64)  [build_ct]
//   per edge e: attn  = hproj[sub] + ct[r_idx][rel]
//               alpha = sigmoid(dot(relu(attn), wa) + wa_b)
//               agg[obj] += alpha * (hidden[sub] + rela_embed[rel])  [atomic]
//   out = agg @ Wh^T  (in place on d_out)
// edge_scatter: 2 edges per wave (lanes 0-31 / 32-63), float2 per lane.
//   R4: contiguous chunk per wave + 4-pair unroll (16 gathers in flight)
//   to attack the measured latency-bound profile (VALU 9.7%, HBM 23.6%).
// ---------------------------------------------------------------------------

// dst[r][a] = sum_k src[r][k] * W[a][k];  64x64 W, row tile of 64.
// NOTE: no __restrict__ on src/dst — used in-place for the final projection
// (each block stages its own 64 rows to LDS before overwriting them).
__global__ __launch_bounds__(256) void rowproj64(const float* src,
                                                 const float* __restrict__ W,
                                                 float* dst, int nrows) {
    __shared__ float Wt[64][65];    // Wt[k][a] = W[a][k]  (padded: conflict-free)
    __shared__ float4 Sl[64][16];   // 64 rows x 64 cols as float4
    int tid = threadIdx.x;
    for (int i = tid; i < 4096; i += 256) Wt[i & 63][i >> 6] = W[i];
    long r0 = (long)blockIdx.x * 64;
    const float4* src4 = (const float4*)(src + r0 * 64);
    float4* s4 = (float4*)Sl;
    for (int i = tid; i < 1024; i += 256) s4[i] = src4[i];
    __syncthreads();
    int c = tid & 63;            // output column this thread owns
    int rbase = (tid >> 6) * 16; // 16 rows per thread
    float w[64];
#pragma unroll
    for (int k = 0; k < 64; ++k) w[k] = Wt[k][c];  // stride-1 across lanes: conflict-free
#pragma unroll
    for (int r = 0; r < 16; ++r) {
        float a0 = 0.f, a1 = 0.f, a2 = 0.f, a3 = 0.f;
#pragma unroll
        for (int k4 = 0; k4 < 16; ++k4) {
            float4 s = Sl[rbase + r][k4];  // broadcast read (same addr all lanes)
            a0 += s.x * w[4 * k4 + 0];
            a1 += s.y * w[4 * k4 + 1];
            a2 += s.z * w[4 * k4 + 2];
            a3 += s.w * w[4 * k4 + 3];
        }
        dst[(r0 + rbase + r) * 64 + c] = (a0 + a1) + (a2 + a3);  // coalesced
    }
}

// out[r][a] = dot(rela[r], W[a])   (tiny: 401 x 64)
__global__ void relproj(const float* __restrict__ rela,
                        const float* __restrict__ W,
                        float* __restrict__ out) {
    int r = blockIdx.x, a = threadIdx.x;
    __shared__ float h[64];
    h[a] = rela[r * 64 + a];
    __syncthreads();
    float acc = 0.f;
#pragma unroll
    for (int k = 0; k < 64; ++k) acc += h[k] * W[a * 64 + k];
    out[r * 64 + a] = acc;
}

// out[b][a] = dot(rela[q_rel[b]], Wqr[a]) + bqr[a]   (8 x 64)
__global__ void qrproj(const float* __restrict__ rela,
                       const int* __restrict__ q_rel,
                       const float* __restrict__ Wqr,
                       const float* __restrict__ bqr,
                       float* __restrict__ out) {
    int b = blockIdx.x, a = threadIdx.x;
    int qr = q_rel[b];
    __shared__ float h[64];
    h[a] = rela[qr * 64 + a];
    __syncthreads();
    float acc = bqr[a];
#pragma unroll
    for (int k = 0; k < 64; ++k) acc += h[k] * Wqr[a * 64 + k];
    out[b * 64 + a] = acc;
}

// ct[(b*n_rel_tot + r)*64 + a] = hrproj[r][a] + hqrproj[b][a]
__global__ void build_ct(const float* __restrict__ hrproj,
                         const float* __restrict__ hqrproj,
                         float* __restrict__ ct, int n_rel_tot) {
    int idx = blockIdx.x;        // b * n_rel_tot + r
    int a = threadIdx.x;
    int b = idx / n_rel_tot, r = idx - b * n_rel_tot;
    ct[(size_t)idx * 64 + a] = hrproj[r * 64 + a] + hqrproj[b * 64 + a];
}

// 2 edges per wave: lanes 0-31 handle edge 2p, lanes 32-63 handle edge 2p+1.
// Each lane covers 2 features (float2). Each wave owns a CONTIGUOUS pair
// range (sequential edge-record s_loads), unrolled 4 pairs so 16 gathers
// are in flight before any reduce consumes them.
__global__ __launch_bounds__(256) void edge_scatter(
    const int* __restrict__ edges, int E,
    const float* __restrict__ hidden,
    const float* __restrict__ rela,
    const float* __restrict__ hproj,
    const float* __restrict__ ct, int n_rel_tot,
    const float* __restrict__ wa,
    const float* __restrict__ wab_p,
    float* __restrict__ agg) {
    int lane = threadIdx.x & 63;
    int half = lane >> 5;        // which edge of the pair this lane works on
    int li   = lane & 31;        // lane within the half; features {2li, 2li+1}
    int wid = __builtin_amdgcn_readfirstlane(
        (int)((blockIdx.x * blockDim.x + threadIdx.x) >> 6));
    int nw = (int)((gridDim.x * blockDim.x) >> 6);
    int npairs = (E + 1) >> 1;
    int per = (npairs + nw - 1) / nw;
    int p0 = wid * per;
    int p1 = min(p0 + per, npairs);

    const float2* hidden2 = (const float2*)hidden;
    const float2* rela2   = (const float2*)rela;
    const float2* hproj2  = (const float2*)hproj;
    const float2* ct2     = (const float2*)ct;
    float2 wav = ((const float2*)wa)[li];
    float wab = wab_p[0];

    int p = p0;
    // main body: 4 pairs (8 edges) per iteration, all edges valid
    for (; p + 4 <= p1 && 2 * (p + 4) <= E; p += 4) {
        float2 hp[4], cv[4], hh[4], rl[4];
        int objs[4];
#pragma unroll
        for (int j = 0; j < 4; ++j) {
            // records for edges 2(p+j), 2(p+j)+1 are 48 contiguous bytes:
            // uniform base -> scalar loads with immediate offsets
            const int* ed = edges + (size_t)(2 * (p + j)) * 6;
            int r_idx = half ? ed[6]  : ed[0];
            int rel   = half ? ed[8]  : ed[2];
            int sub   = half ? ed[10] : ed[4];
            objs[j]   = half ? ed[11] : ed[5];
            size_t sb = (size_t)sub * 32 + li;
            hp[j] = hproj2[sb];
            cv[j] = ct2[((size_t)r_idx * n_rel_tot + rel) * 32 + li];
            hh[j] = hidden2[sb];
            rl[j] = rela2[(size_t)rel * 32 + li];
        }
#pragma unroll
        for (int j = 0; j < 4; ++j) {
            float t = fmaxf(hp[j].x + cv[j].x, 0.f) * wav.x
                    + fmaxf(hp[j].y + cv[j].y, 0.f) * wav.y;
#pragma unroll
            for (int o = 16; o; o >>= 1) t += __shfl_xor(t, o, 64);
            float alpha = 1.f / (1.f + __expf(-(t + wab)));
            float* dst = &agg[((size_t)objs[j] * 32 + li) * 2];
            unsafeAtomicAdd(dst + 0, alpha * (hh[j].x + rl[j].x));
            unsafeAtomicAdd(dst + 1, alpha * (hh[j].y + rl[j].y));
        }
    }
    // remainder (few pairs; handles odd E)
    for (; p < p1; ++p) {
        int e0 = 2 * p, e1 = e0 + 1;
        bool v1 = e1 < E;
        const int* ed0 = edges + (size_t)e0 * 6;
        const int* ed1 = edges + (size_t)(v1 ? e1 : e0) * 6;
        int r_idx = half ? ed1[0] : ed0[0];
        int rel   = half ? ed1[2] : ed0[2];
        int sub   = half ? ed1[4] : ed0[4];
        int obj   = half ? ed1[5] : ed0[5];
        size_t sb = (size_t)sub * 32 + li;
        float2 hp = hproj2[sb];
        float2 cv = ct2[((size_t)r_idx * n_rel_tot + rel) * 32 + li];
        float t = fmaxf(hp.x + cv.x, 0.f) * wav.x
                + fmaxf(hp.y + cv.y, 0.f) * wav.y;
#pragma unroll
        for (int o = 16; o; o >>= 1) t += __shfl_xor(t, o, 64);
        float alpha = 1.f / (1.f + __expf(-(t + wab)));
        float2 h = hidden2[sb];
        float2 rl = rela2[(size_t)rel * 32 + li];
        if (!half || v1) {
            float* dst = &agg[((size_t)obj * 32 + li) * 2];
            unsafeAtomicAdd(dst + 0, alpha * (h.x + rl.x));
            unsafeAtomicAdd(dst + 1, alpha * (h.y + rl.y));
        }
    }
}

extern "C" void kernel_launch(void* const* d_in, const int* in_sizes, int n_in,
                              void* d_out, int out_size, void* d_ws, size_t ws_size,
                              hipStream_t stream) {
    const int* q_rel    = (const int*)d_in[1];
    const float* hidden = (const float*)d_in[2];
    const int* edges    = (const int*)d_in[3];
    const float* rela   = (const float*)d_in[7];
    const float* Ws     = (const float*)d_in[8];
    const float* Wr     = (const float*)d_in[9];
    const float* WqrW   = (const float*)d_in[10];
    const float* Wqrb   = (const float*)d_in[11];
    const float* waW    = (const float*)d_in[12];
    const float* wab    = (const float*)d_in[13];
    const float* Wh     = (const float*)d_in[14];

    int E = in_sizes[3] / 6;            // 1,000,000
    int n_node = in_sizes[4] / 2;       // 200,000
    int n_rel_tot = in_sizes[7] / 64;   // 401
    int B = in_sizes[0];                // 8

    float* agg = (float*)d_out;                        // n_node*64 accumulator
    float* hproj   = (float*)d_ws;                     // n_node*64
    float* hrproj  = hproj + (size_t)n_node * 64;      // n_rel_tot*64
    float* hqrproj = hrproj + (size_t)n_rel_tot * 64;  // B*64
    float* ct      = hqrproj + (size_t)B * 64;         // B*n_rel_tot*64

    hipMemsetAsync(d_out, 0, (size_t)out_size * sizeof(float), stream);
    rowproj64<<<n_node / 64, 256, 0, stream>>>(hidden, Ws, hproj, n_node);
    relproj<<<n_rel_tot, 64, 0, stream>>>(rela, Wr, hrproj);
    qrproj<<<B, 64, 0, stream>>>(rela, q_rel, WqrW, Wqrb, hqrproj);
    build_ct<<<B * n_rel_tot, 64, 0, stream>>>(hrproj, hqrproj, ct, n_rel_tot);
    edge_scatter<<<2048, 256, 0, stream>>>(edges, E, hidden, rela, hproj,
                                           ct, n_rel_tot, waW, wab, agg);
    rowproj64<<<n_node / 64, 256, 0, stream>>>(agg, Wh, agg, n_node);
}

// Round 6
// 458.471 us; speedup vs baseline: 1.4249x; 1.4249x over previous
//
#include <hip/hip_runtime.h>
#include <hip/hip_bf16.h>

// ---------------------------------------------------------------------------
// GNN layer, atomic-free aggregation (R6 = R5 resubmit + k_aggregate pipeline):
//   hproj   = hidden @ Ws^T                         [rowproj64]
//   hrproj  = rela_embed @ Wr^T; hqrproj = ...      [relproj/qrproj]
//   ct[b][r] = hrproj[r] + hqrproj[b]               [build_ct]
//   CSR build: deg -> scan -> rowptr/cursor         [k_count, k_scan_*]
//   k_scatter: alpha_e = sigmoid(wa . relu(hproj[sub]+ct[r_idx][rel]) + b)
//              pos = cursor[obj]++; key[pos]=sub|(rel<<18); aval[pos]=alpha
//   k_aggregate: per node n: agg[n] = sum_j alpha_j*(hidden[sub_j]+rela[rel_j])
//              (contiguous slice, zero atomics, one coalesced store)
//   out = agg @ Wh^T (in place on d_out)            [rowproj64]
// R4 evidence: 64M f32 atomics caused 500 MB/dispatch RMW write traffic and
// were insensitive to gather MLP -> removed the atomics instead.
// ---------------------------------------------------------------------------

// dst[r][a] = sum_k src[r][k] * W[a][k];  64x64 W, row tile of 64.
// NOTE: no __restrict__ on src/dst — used in-place for the final projection.
__global__ __launch_bounds__(256) void rowproj64(const float* src,
                                                 const float* __restrict__ W,
                                                 float* dst, int nrows) {
    __shared__ float Wt[64][65];
    __shared__ float4 Sl[64][16];
    int tid = threadIdx.x;
    for (int i = tid; i < 4096; i += 256) Wt[i & 63][i >> 6] = W[i];
    long r0 = (long)blockIdx.x * 64;
    const float4* src4 = (const float4*)(src + r0 * 64);
    float4* s4 = (float4*)Sl;
    for (int i = tid; i < 1024; i += 256) s4[i] = src4[i];
    __syncthreads();
    int c = tid & 63;
    int rbase = (tid >> 6) * 16;
    float w[64];
#pragma unroll
    for (int k = 0; k < 64; ++k) w[k] = Wt[k][c];
#pragma unroll
    for (int r = 0; r < 16; ++r) {
        float a0 = 0.f, a1 = 0.f, a2 = 0.f, a3 = 0.f;
#pragma unroll
        for (int k4 = 0; k4 < 16; ++k4) {
            float4 s = Sl[rbase + r][k4];
            a0 += s.x * w[4 * k4 + 0];
            a1 += s.y * w[4 * k4 + 1];
            a2 += s.z * w[4 * k4 + 2];
            a3 += s.w * w[4 * k4 + 3];
        }
        dst[(r0 + rbase + r) * 64 + c] = (a0 + a1) + (a2 + a3);
    }
}

__global__ void relproj(const float* __restrict__ rela,
                        const float* __restrict__ W,
                        float* __restrict__ out) {
    int r = blockIdx.x, a = threadIdx.x;
    __shared__ float h[64];
    h[a] = rela[r * 64 + a];
    __syncthreads();
    float acc = 0.f;
#pragma unroll
    for (int k = 0; k < 64; ++k) acc += h[k] * W[a * 64 + k];
    out[r * 64 + a] = acc;
}

__global__ void qrproj(const float* __restrict__ rela,
                       const int* __restrict__ q_rel,
                       const float* __restrict__ Wqr,
                       const float* __restrict__ bqr,
                       float* __restrict__ out) {
    int b = blockIdx.x, a = threadIdx.x;
    int qr = q_rel[b];
    __shared__ float h[64];
    h[a] = rela[qr * 64 + a];
    __syncthreads();
    float acc = bqr[a];
#pragma unroll
    for (int k = 0; k < 64; ++k) acc += h[k] * Wqr[a * 64 + k];
    out[b * 64 + a] = acc;
}

__global__ void build_ct(const float* __restrict__ hrproj,
                         const float* __restrict__ hqrproj,
                         float* __restrict__ ct, int n_rel_tot) {
    int idx = blockIdx.x;  // b * n_rel_tot + r
    int a = threadIdx.x;
    int b = idx / n_rel_tot, r = idx - b * n_rel_tot;
    ct[(size_t)idx * 64 + a] = hrproj[r * 64 + a] + hqrproj[b * 64 + a];
}

// ---- CSR build -------------------------------------------------------------
__global__ void k_count(const int* __restrict__ edges, int E,
                        int* __restrict__ deg) {
    int e = blockIdx.x * blockDim.x + threadIdx.x;
    if (e < E) atomicAdd(&deg[edges[(size_t)e * 6 + 5]], 1);
}

#define SCAN_BS 256
// block b scans 1024 elements of deg into exclusive prefix (in-place into
// rowptr w/o global offset); bsum[b] = block total.
__global__ __launch_bounds__(SCAN_BS) void k_scan_block(
    const int* __restrict__ deg, int N,
    int* __restrict__ rowptr, int* __restrict__ bsum) {
    __shared__ int sh[SCAN_BS];
    int t = threadIdx.x, b = blockIdx.x;
    int base = b * 1024 + t * 4;
    int d0 = (base + 0 < N) ? deg[base + 0] : 0;
    int d1 = (base + 1 < N) ? deg[base + 1] : 0;
    int d2 = (base + 2 < N) ? deg[base + 2] : 0;
    int d3 = (base + 3 < N) ? deg[base + 3] : 0;
    int s = d0 + d1 + d2 + d3;
    sh[t] = s;
    __syncthreads();
    for (int o = 1; o < SCAN_BS; o <<= 1) {
        int v = (t >= o) ? sh[t - o] : 0;
        __syncthreads();
        sh[t] += v;
        __syncthreads();
    }
    int run = sh[t] - s;  // exclusive
    if (t == SCAN_BS - 1) bsum[b] = sh[t];
    if (base + 0 < N) rowptr[base + 0] = run;  run += d0;
    if (base + 1 < N) rowptr[base + 1] = run;  run += d1;
    if (base + 2 < N) rowptr[base + 2] = run;  run += d2;
    if (base + 3 < N) rowptr[base + 3] = run;
}

__global__ __launch_bounds__(SCAN_BS) void k_scan_partials(
    const int* __restrict__ bsum, int* __restrict__ boffs, int NB) {
    __shared__ int sh[SCAN_BS];
    int t = threadIdx.x;
    int v = (t < NB) ? bsum[t] : 0;
    sh[t] = v;
    __syncthreads();
    for (int o = 1; o < SCAN_BS; o <<= 1) {
        int u = (t >= o) ? sh[t - o] : 0;
        __syncthreads();
        sh[t] += u;
        __syncthreads();
    }
    if (t < NB) boffs[t] = sh[t] - v;
}

__global__ void k_add_offsets(int* __restrict__ rowptr,
                              int* __restrict__ cursor,
                              const int* __restrict__ boffs, int N, int E) {
    int i = blockIdx.x * blockDim.x + threadIdx.x;
    if (i < N) {
        int v = rowptr[i] + boffs[i >> 10];
        rowptr[i] = v;
        cursor[i] = v;
    }
    if (i == 0) rowptr[N] = E;
}

// ---- alpha + sorted scatter ------------------------------------------------
// 2 edges per wave (lanes 0-31 / 32-63), float2 per lane; contiguous chunk
// per wave so edge records are sequential scalar loads. Per edge: ONE
// atomicAdd (cursor) + 8 B store. No feature atomics.
__global__ __launch_bounds__(256) void k_scatter(
    const int* __restrict__ edges, int E,
    const float* __restrict__ hproj,
    const float* __restrict__ ct, int n_rel_tot,
    const float* __restrict__ wa,
    const float* __restrict__ wab_p,
    int* __restrict__ cursor,
    unsigned int* __restrict__ key,
    float* __restrict__ aval) {
    int lane = threadIdx.x & 63;
    int half = lane >> 5;
    int li   = lane & 31;
    int wid = __builtin_amdgcn_readfirstlane(
        (int)((blockIdx.x * blockDim.x + threadIdx.x) >> 6));
    int nw = (int)((gridDim.x * blockDim.x) >> 6);
    int npairs = (E + 1) >> 1;
    int per = (npairs + nw - 1) / nw;
    int p0 = wid * per;
    int p1 = min(p0 + per, npairs);

    const float2* hproj2 = (const float2*)hproj;
    const float2* ct2    = (const float2*)ct;
    float2 wav = ((const float2*)wa)[li];
    float wab = wab_p[0];

    for (int p = p0; p < p1; ++p) {
        int e0 = 2 * p, e1 = e0 + 1;
        bool v1 = e1 < E;
        const int* ed0 = edges + (size_t)e0 * 6;  // uniform base -> s_load
        const int* ed1 = edges + (size_t)(v1 ? e1 : e0) * 6;
        int r_idx = half ? ed1[0] : ed0[0];
        int rel   = half ? ed1[2] : ed0[2];
        int sub   = half ? ed1[4] : ed0[4];
        int obj   = half ? ed1[5] : ed0[5];

        size_t sb = (size_t)sub * 32 + li;
        float2 hp = hproj2[sb];
        float2 cv = ct2[((size_t)r_idx * n_rel_tot + rel) * 32 + li];
        float t = fmaxf(hp.x + cv.x, 0.f) * wav.x
                + fmaxf(hp.y + cv.y, 0.f) * wav.y;
#pragma unroll
        for (int o = 16; o; o >>= 1) t += __shfl_xor(t, o, 64);
        float alpha = 1.f / (1.f + __expf(-(t + wab)));

        if (li == 0 && (!half || v1)) {
            int pos = atomicAdd(&cursor[obj], 1);
            key[pos] = (unsigned int)sub | ((unsigned int)rel << 18);
            aval[pos] = alpha;
        }
    }
}

// ---- gather-based aggregation (atomic-free) --------------------------------
// One wave per node; lane = feature. Edge slice is contiguous -> scalar
// loads; per-edge gathers are 256 B coalesced; one 256 B store per node.
// 2-deep pipeline: next edge's key/alpha loaded while current is consumed.
__global__ __launch_bounds__(256) void k_aggregate(
    const int* __restrict__ rowptr,
    const unsigned int* __restrict__ key,
    const float* __restrict__ aval,
    const float* __restrict__ hidden,
    const float* __restrict__ rela,
    float* __restrict__ agg, int N) {
    int lane = threadIdx.x & 63;
    int w = (int)((blockIdx.x * blockDim.x + threadIdx.x) >> 6);
    if (w >= N) return;
    int n = __builtin_amdgcn_readfirstlane(w);
    int s = rowptr[n], e = rowptr[n + 1];
    float acc = 0.f;
    if (s < e) {
        unsigned int k = key[s];   // wave-uniform scalar load
        float a = aval[s];
        for (int j = s + 1; j < e; ++j) {
            unsigned int kn = key[j];   // prefetch next
            float an = aval[j];
            int sub = (int)(k & 0x3FFFFu);
            int rel = (int)(k >> 18);
            acc += a * (hidden[(size_t)sub * 64 + lane] + rela[rel * 64 + lane]);
            k = kn;
            a = an;
        }
        int sub = (int)(k & 0x3FFFFu);
        int rel = (int)(k >> 18);
        acc += a * (hidden[(size_t)sub * 64 + lane] + rela[rel * 64 + lane]);
    }
    agg[(size_t)n * 64 + lane] = acc;
}

extern "C" void kernel_launch(void* const* d_in, const int* in_sizes, int n_in,
                              void* d_out, int out_size, void* d_ws, size_t ws_size,
                              hipStream_t stream) {
    const int* q_rel    = (const int*)d_in[1];
    const float* hidden = (const float*)d_in[2];
    const int* edges    = (const int*)d_in[3];
    const float* rela   = (const float*)d_in[7];
    const float* Ws     = (const float*)d_in[8];
    const float* Wr     = (const float*)d_in[9];
    const float* WqrW   = (const float*)d_in[10];
    const float* Wqrb   = (const float*)d_in[11];
    const float* waW    = (const float*)d_in[12];
    const float* wab    = (const float*)d_in[13];
    const float* Wh     = (const float*)d_in[14];

    int E = in_sizes[3] / 6;            // 1,000,000
    int n_node = in_sizes[4] / 2;       // 200,000
    int n_rel_tot = in_sizes[7] / 64;   // 401
    int B = in_sizes[0];                // 8
    int NB = (n_node + 1023) / 1024;    // scan blocks (196 <= 256)

    float* agg = (float*)d_out;                          // n_node*64
    char* w = (char*)d_ws;
    float* hproj   = (float*)w;                w += (size_t)n_node * 64 * 4;
    float* hrproj  = (float*)w;                w += (size_t)n_rel_tot * 64 * 4;
    float* hqrproj = (float*)w;                w += (size_t)B * 64 * 4;
    float* ct      = (float*)w;                w += (size_t)B * n_rel_tot * 64 * 4;
    float* aval    = (float*)w;                w += (size_t)E * 4;
    unsigned int* key = (unsigned int*)w;      w += (size_t)E * 4;
    int* deg    = (int*)w;                     w += (size_t)n_node * 4;
    int* cursor = (int*)w;                     w += (size_t)n_node * 4;
    int* rowptr = (int*)w;                     w += (size_t)(n_node + 1) * 4;
    int* bsum   = (int*)w;                     w += (size_t)NB * 4;
    int* boffs  = (int*)w;                     w += (size_t)NB * 4;

    // projections + combined rel/query table
    rowproj64<<<n_node / 64, 256, 0, stream>>>(hidden, Ws, hproj, n_node);
    relproj<<<n_rel_tot, 64, 0, stream>>>(rela, Wr, hrproj);
    qrproj<<<B, 64, 0, stream>>>(rela, q_rel, WqrW, Wqrb, hqrproj);
    build_ct<<<B * n_rel_tot, 64, 0, stream>>>(hrproj, hqrproj, ct, n_rel_tot);

    // CSR build
    hipMemsetAsync(deg, 0, (size_t)n_node * 4, stream);
    k_count<<<(E + 255) / 256, 256, 0, stream>>>(edges, E, deg);
    k_scan_block<<<NB, SCAN_BS, 0, stream>>>(deg, n_node, rowptr, bsum);
    k_scan_partials<<<1, SCAN_BS, 0, stream>>>(bsum, boffs, NB);
    k_add_offsets<<<(n_node + 255) / 256, 256, 0, stream>>>(rowptr, cursor,
                                                            boffs, n_node, E);

    // alpha + sorted scatter, then atomic-free aggregate, then out-projection
    k_scatter<<<2048, 256, 0, stream>>>(edges, E, hproj, ct, n_rel_tot,
                                        waW, wab, cursor, key, aval);
    k_aggregate<<<(n_node * 64 + 255) / 256, 256, 0, stream>>>(
        rowptr, key, aval, hidden, rela, agg, n_node);
    rowproj64<<<n_node / 64, 256, 0, stream>>>(agg, Wh, agg, n_node);
}

// Round 9
// 448.431 us; speedup vs baseline: 1.4568x; 1.0224x over previous
//
#include <hip/hip_runtime.h>
#include <hip/hip_bf16.h>

// ---------------------------------------------------------------------------
// GNN layer, fused atomic-free pipeline (R9 = R7 resubmit):
//   hproj = hidden @ Ws^T                                  [rowproj64]
//   ct[rel*8+b] = rela[rel]@Wr^T + rela[q_rel[b]]@Wqr^T+b  [k_ct]
//   CSR build: deg -> scan -> rowptr/cursor                [k_count,k_scan_*]
//   k_key: pos = cursor[obj]++; key[pos] = sub | (rel*8+r_idx)<<18
//   k_agg (FUSED, per node wave, lane=feature):
//     for each edge j: alpha = sigmoid(wa . relu(hproj[sub]+ct[cr]) + b)
//                      acc += alpha*(hidden[sub]+rela[rel])
//     4 gathers/edge, 2-deep pipeline, zero feature atomics, 1 store/node
//   out = agg @ Wh^T (in place on d_out)                   [rowproj64]
// R6 evidence: both edge passes latency-bound (27% HBM, 31% VALU) with
// conserved gather traffic -> fuse for 2x MLP/wave and one fewer pass.
// ---------------------------------------------------------------------------

// dst[r][a] = sum_k src[r][k] * W[a][k];  64x64 W, row tile of 64.
// NOTE: no __restrict__ on src/dst — used in-place for the final projection.
__global__ __launch_bounds__(256) void rowproj64(const float* src,
                                                 const float* __restrict__ W,
                                                 float* dst, int nrows) {
    __shared__ float Wt[64][65];
    __shared__ float4 Sl[64][16];
    int tid = threadIdx.x;
    for (int i = tid; i < 4096; i += 256) Wt[i & 63][i >> 6] = W[i];
    long r0 = (long)blockIdx.x * 64;
    const float4* src4 = (const float4*)(src + r0 * 64);
    float4* s4 = (float4*)Sl;
    for (int i = tid; i < 1024; i += 256) s4[i] = src4[i];
    __syncthreads();
    int c = tid & 63;
    int rbase = (tid >> 6) * 16;
    float w[64];
#pragma unroll
    for (int k = 0; k < 64; ++k) w[k] = Wt[k][c];
#pragma unroll
    for (int r = 0; r < 16; ++r) {
        float a0 = 0.f, a1 = 0.f, a2 = 0.f, a3 = 0.f;
#pragma unroll
        for (int k4 = 0; k4 < 16; ++k4) {
            float4 s = Sl[rbase + r][k4];
            a0 += s.x * w[4 * k4 + 0];
            a1 += s.y * w[4 * k4 + 1];
            a2 += s.z * w[4 * k4 + 2];
            a3 += s.w * w[4 * k4 + 3];
        }
        dst[(r0 + rbase + r) * 64 + c] = (a0 + a1) + (a2 + a3);
    }
}

// ct[rel*8+b][a] = (rela[rel]@Wr^T)[a] + (rela[q_rel[b]]@Wqr^T)[a] + bqr[a]
// One block per rel (401 blocks x 64 threads). B is <= 8 by harness spec.
__global__ void k_ct(const float* __restrict__ rela,
                     const int* __restrict__ q_rel,
                     const float* __restrict__ Wr,
                     const float* __restrict__ Wqr,
                     const float* __restrict__ bqr,
                     float* __restrict__ ct, int B) {
    int rel = blockIdx.x, a = threadIdx.x;
    __shared__ float hr[64];
    __shared__ float hq[8][64];
    hr[a] = rela[(size_t)rel * 64 + a];
    for (int b = 0; b < B; ++b) hq[b][a] = rela[(size_t)q_rel[b] * 64 + a];
    __syncthreads();
    float accr = 0.f;
#pragma unroll
    for (int k = 0; k < 64; ++k) accr += hr[k] * Wr[a * 64 + k];
    for (int b = 0; b < B; ++b) {
        float acc = bqr[a];
#pragma unroll
        for (int k = 0; k < 64; ++k) acc += hq[b][k] * Wqr[a * 64 + k];
        ct[((size_t)rel * 8 + b) * 64 + a] = accr + acc;
    }
}

// ---- CSR build -------------------------------------------------------------
__global__ void k_count(const int* __restrict__ edges, int E,
                        int* __restrict__ deg) {
    int e = blockIdx.x * blockDim.x + threadIdx.x;
    if (e < E) atomicAdd(&deg[edges[(size_t)e * 6 + 5]], 1);
}

#define SCAN_BS 256
__global__ __launch_bounds__(SCAN_BS) void k_scan_block(
    const int* __restrict__ deg, int N,
    int* __restrict__ rowptr, int* __restrict__ bsum) {
    __shared__ int sh[SCAN_BS];
    int t = threadIdx.x, b = blockIdx.x;
    int base = b * 1024 + t * 4;
    int d0 = (base + 0 < N) ? deg[base + 0] : 0;
    int d1 = (base + 1 < N) ? deg[base + 1] : 0;
    int d2 = (base + 2 < N) ? deg[base + 2] : 0;
    int d3 = (base + 3 < N) ? deg[base + 3] : 0;
    int s = d0 + d1 + d2 + d3;
    sh[t] = s;
    __syncthreads();
    for (int o = 1; o < SCAN_BS; o <<= 1) {
        int v = (t >= o) ? sh[t - o] : 0;
        __syncthreads();
        sh[t] += v;
        __syncthreads();
    }
    int run = sh[t] - s;  // exclusive
    if (t == SCAN_BS - 1) bsum[b] = sh[t];
    if (base + 0 < N) rowptr[base + 0] = run;  run += d0;
    if (base + 1 < N) rowptr[base + 1] = run;  run += d1;
    if (base + 2 < N) rowptr[base + 2] = run;  run += d2;
    if (base + 3 < N) rowptr[base + 3] = run;
}

__global__ __launch_bounds__(SCAN_BS) void k_scan_partials(
    const int* __restrict__ bsum, int* __restrict__ boffs, int NB) {
    __shared__ int sh[SCAN_BS];
    int t = threadIdx.x;
    int v = (t < NB) ? bsum[t] : 0;
    sh[t] = v;
    __syncthreads();
    for (int o = 1; o < SCAN_BS; o <<= 1) {
        int u = (t >= o) ? sh[t - o] : 0;
        __syncthreads();
        sh[t] += u;
        __syncthreads();
    }
    if (t < NB) boffs[t] = sh[t] - v;
}

__global__ void k_add_offsets(int* __restrict__ rowptr,
                              int* __restrict__ cursor,
                              const int* __restrict__ boffs, int N, int E) {
    int i = blockIdx.x * blockDim.x + threadIdx.x;
    if (i < N) {
        int v = rowptr[i] + boffs[i >> 10];
        rowptr[i] = v;
        cursor[i] = v;
    }
    if (i == 0) rowptr[N] = E;
}

// ---- key scatter (thread per edge; 1 atomic + 8 B store) -------------------
__global__ void k_key(const int* __restrict__ edges, int E,
                      int* __restrict__ cursor,
                      unsigned int* __restrict__ key) {
    int e = blockIdx.x * blockDim.x + threadIdx.x;
    if (e >= E) return;
    const int* ed = edges + (size_t)e * 6;
    int r_idx = ed[0], rel = ed[2], sub = ed[4], obj = ed[5];
    int pos = atomicAdd(&cursor[obj], 1);
    key[pos] = (unsigned int)sub | ((unsigned int)(rel * 8 + r_idx) << 18);
}

// ---- FUSED alpha + aggregation (atomic-free) -------------------------------
// One wave per node; lane = feature. Per edge: 4 coalesced 256 B gathers
// (2-deep pipelined), 6-shuffle reduce for the attention dot, sigmoid, fma.
// One coalesced 256 B store per node. key/rowptr loads are wave-uniform.
__global__ __launch_bounds__(256) void k_agg(
    const int* __restrict__ rowptr,
    const unsigned int* __restrict__ key,
    const float* __restrict__ hproj,
    const float* __restrict__ ct,
    const float* __restrict__ hidden,
    const float* __restrict__ rela,
    const float* __restrict__ wa,
    const float* __restrict__ wab_p,
    float* __restrict__ agg, int N) {
    int lane = threadIdx.x & 63;
    int w = (int)((blockIdx.x * blockDim.x + threadIdx.x) >> 6);
    if (w >= N) return;
    int n = __builtin_amdgcn_readfirstlane(w);
    int s = rowptr[n], e = rowptr[n + 1];
    float wav = wa[lane];
    float wab = wab_p[0];
    float acc = 0.f;
    if (s < e) {
        unsigned int k0 = key[s];                 // wave-uniform -> s_load
        int sub = (int)(k0 & 0x3FFFFu);
        int cr  = (int)(k0 >> 18);                // rel*8 + r_idx
        float hp = hproj[(size_t)sub * 64 + lane];
        float cv = ct[(size_t)cr * 64 + lane];
        float hd = hidden[(size_t)sub * 64 + lane];
        float rl = rela[(size_t)(cr >> 3) * 64 + lane];
        for (int j = s + 1; j < e; ++j) {
            unsigned int k1 = key[j];             // prefetch next edge
            int sub1 = (int)(k1 & 0x3FFFFu);
            int cr1  = (int)(k1 >> 18);
            float hp1 = hproj[(size_t)sub1 * 64 + lane];
            float cv1 = ct[(size_t)cr1 * 64 + lane];
            float hd1 = hidden[(size_t)sub1 * 64 + lane];
            float rl1 = rela[(size_t)(cr1 >> 3) * 64 + lane];
            float t = fmaxf(hp + cv, 0.f) * wav;
#pragma unroll
            for (int o = 32; o; o >>= 1) t += __shfl_xor(t, o, 64);
            float alpha = 1.f / (1.f + __expf(-(t + wab)));
            acc += alpha * (hd + rl);
            hp = hp1; cv = cv1; hd = hd1; rl = rl1;
        }
        float t = fmaxf(hp + cv, 0.f) * wav;
#pragma unroll
        for (int o = 32; o; o >>= 1) t += __shfl_xor(t, o, 64);
        float alpha = 1.f / (1.f + __expf(-(t + wab)));
        acc += alpha * (hd + rl);
    }
    agg[(size_t)n * 64 + lane] = acc;
}

extern "C" void kernel_launch(void* const* d_in, const int* in_sizes, int n_in,
                              void* d_out, int out_size, void* d_ws, size_t ws_size,
                              hipStream_t stream) {
    const int* q_rel    = (const int*)d_in[1];
    const float* hidden = (const float*)d_in[2];
    const int* edges    = (const int*)d_in[3];
    const float* rela   = (const float*)d_in[7];
    const float* Ws     = (const float*)d_in[8];
    const float* Wr     = (const float*)d_in[9];
    const float* WqrW   = (const float*)d_in[10];
    const float* Wqrb   = (const float*)d_in[11];
    const float* waW    = (const float*)d_in[12];
    const float* wab    = (const float*)d_in[13];
    const float* Wh     = (const float*)d_in[14];

    int E = in_sizes[3] / 6;            // 1,000,000
    int n_node = in_sizes[4] / 2;       // 200,000
    int n_rel_tot = in_sizes[7] / 64;   // 401
    int B = in_sizes[0];                // 8 (k_ct/k_key assume <= 8)
    int NB = (n_node + 1023) / 1024;    // scan blocks (196 <= 256)

    float* agg = (float*)d_out;                          // n_node*64
    char* w = (char*)d_ws;
    float* hproj = (float*)w;                  w += (size_t)n_node * 64 * 4;
    float* ct    = (float*)w;                  w += (size_t)n_rel_tot * 8 * 64 * 4;
    unsigned int* key = (unsigned int*)w;      w += (size_t)E * 4;
    int* deg    = (int*)w;                     w += (size_t)n_node * 4;
    int* cursor = (int*)w;                     w += (size_t)n_node * 4;
    int* rowptr = (int*)w;                     w += (size_t)(n_node + 1) * 4;
    int* bsum   = (int*)w;                     w += (size_t)NB * 4;
    int* boffs  = (int*)w;                     w += (size_t)NB * 4;

    // node projection + combined attention table
    rowproj64<<<n_node / 64, 256, 0, stream>>>(hidden, Ws, hproj, n_node);
    k_ct<<<n_rel_tot, 64, 0, stream>>>(rela, q_rel, Wr, WqrW, Wqrb, ct, B);

    // CSR build
    hipMemsetAsync(deg, 0, (size_t)n_node * 4, stream);
    k_count<<<(E + 255) / 256, 256, 0, stream>>>(edges, E, deg);
    k_scan_block<<<NB, SCAN_BS, 0, stream>>>(deg, n_node, rowptr, bsum);
    k_scan_partials<<<1, SCAN_BS, 0, stream>>>(bsum, boffs, NB);
    k_add_offsets<<<(n_node + 255) / 256, 256, 0, stream>>>(rowptr, cursor,
                                                            boffs, n_node, E);

    // key scatter, fused alpha+aggregate, out-projection
    k_key<<<(E + 255) / 256, 256, 0, stream>>>(edges, E, cursor, key);
    k_agg<<<(n_node * 64 + 255) / 256, 256, 0, stream>>>(
        rowptr, key, hproj, ct, hidden, rela, waW, wab, agg, n_node);
    rowproj64<<<n_node / 64, 256, 0, stream>>>(agg, Wh, agg, n_node);
}

// Round 10
// 401.746 us; speedup vs baseline: 1.6261x; 1.1162x over previous
//
#include <hip/hip_runtime.h>
#include <hip/hip_bf16.h>

// ---------------------------------------------------------------------------
// GNN layer, fused atomic-free pipeline (R10):
//   hproj = hidden @ Ws^T                                  [rowproj64]
//   ct[rel*8+b] = rela[rel]@Wr^T + rela[q_rel[b]]@Wqr^T+b  [k_ct]
//   CSR: k_count (deg + rank[e]) -> scan -> rowptr
//   k_key: pos = rowptr[obj] + rank[e]  (atomic-free)
//   k_agg (2 edges/wave, 32 lanes x float2 each):
//     one gather instruction serves both edges; 5-shuffle reduce and one
//     sigmoid cover both edges -> ~2x less VALU/DS per edge than R9
//   out = agg @ Wh^T (in place on d_out)                   [rowproj64]
// R9 evidence: k_agg VALUBusy 78.5% (VALU-bound), 36 VALU + 6 DS per edge.
// ---------------------------------------------------------------------------

// dst[r][a] = sum_k src[r][k] * W[a][k];  64x64 W, row tile of 64.
// NOTE: no __restrict__ on src/dst — used in-place for the final projection.
__global__ __launch_bounds__(256) void rowproj64(const float* src,
                                                 const float* __restrict__ W,
                                                 float* dst, int nrows) {
    __shared__ float Wt[64][65];
    __shared__ float4 Sl[64][16];
    int tid = threadIdx.x;
    for (int i = tid; i < 4096; i += 256) Wt[i & 63][i >> 6] = W[i];
    long r0 = (long)blockIdx.x * 64;
    const float4* src4 = (const float4*)(src + r0 * 64);
    float4* s4 = (float4*)Sl;
    for (int i = tid; i < 1024; i += 256) s4[i] = src4[i];
    __syncthreads();
    int c = tid & 63;
    int rbase = (tid >> 6) * 16;
    float w[64];
#pragma unroll
    for (int k = 0; k < 64; ++k) w[k] = Wt[k][c];
#pragma unroll
    for (int r = 0; r < 16; ++r) {
        float a0 = 0.f, a1 = 0.f, a2 = 0.f, a3 = 0.f;
#pragma unroll
        for (int k4 = 0; k4 < 16; ++k4) {
            float4 s = Sl[rbase + r][k4];
            a0 += s.x * w[4 * k4 + 0];
            a1 += s.y * w[4 * k4 + 1];
            a2 += s.z * w[4 * k4 + 2];
            a3 += s.w * w[4 * k4 + 3];
        }
        dst[(r0 + rbase + r) * 64 + c] = (a0 + a1) + (a2 + a3);
    }
}

// ct[rel*8+b][a] = (rela[rel]@Wr^T)[a] + (rela[q_rel[b]]@Wqr^T)[a] + bqr[a]
__global__ void k_ct(const float* __restrict__ rela,
                     const int* __restrict__ q_rel,
                     const float* __restrict__ Wr,
                     const float* __restrict__ Wqr,
                     const float* __restrict__ bqr,
                     float* __restrict__ ct, int B) {
    int rel = blockIdx.x, a = threadIdx.x;
    __shared__ float hr[64];
    __shared__ float hq[8][64];
    hr[a] = rela[(size_t)rel * 64 + a];
    for (int b = 0; b < B; ++b) hq[b][a] = rela[(size_t)q_rel[b] * 64 + a];
    __syncthreads();
    float accr = 0.f;
#pragma unroll
    for (int k = 0; k < 64; ++k) accr += hr[k] * Wr[a * 64 + k];
    for (int b = 0; b < B; ++b) {
        float acc = bqr[a];
#pragma unroll
        for (int k = 0; k < 64; ++k) acc += hq[b][k] * Wqr[a * 64 + k];
        ct[((size_t)rel * 8 + b) * 64 + a] = accr + acc;
    }
}

// ---- CSR build -------------------------------------------------------------
// rank[e] = this edge's arrival index among edges sharing its obj.
__global__ void k_count(const int* __restrict__ edges, int E,
                        int* __restrict__ deg, int* __restrict__ rank) {
    int e = blockIdx.x * blockDim.x + threadIdx.x;
    if (e < E) rank[e] = atomicAdd(&deg[edges[(size_t)e * 6 + 5]], 1);
}

#define SCAN_BS 256
__global__ __launch_bounds__(SCAN_BS) void k_scan_block(
    const int* __restrict__ deg, int N,
    int* __restrict__ rowptr, int* __restrict__ bsum) {
    __shared__ int sh[SCAN_BS];
    int t = threadIdx.x, b = blockIdx.x;
    int base = b * 1024 + t * 4;
    int d0 = (base + 0 < N) ? deg[base + 0] : 0;
    int d1 = (base + 1 < N) ? deg[base + 1] : 0;
    int d2 = (base + 2 < N) ? deg[base + 2] : 0;
    int d3 = (base + 3 < N) ? deg[base + 3] : 0;
    int s = d0 + d1 + d2 + d3;
    sh[t] = s;
    __syncthreads();
    for (int o = 1; o < SCAN_BS; o <<= 1) {
        int v = (t >= o) ? sh[t - o] : 0;
        __syncthreads();
        sh[t] += v;
        __syncthreads();
    }
    int run = sh[t] - s;  // exclusive
    if (t == SCAN_BS - 1) bsum[b] = sh[t];
    if (base + 0 < N) rowptr[base + 0] = run;  run += d0;
    if (base + 1 < N) rowptr[base + 1] = run;  run += d1;
    if (base + 2 < N) rowptr[base + 2] = run;  run += d2;
    if (base + 3 < N) rowptr[base + 3] = run;
}

__global__ __launch_bounds__(SCAN_BS) void k_scan_partials(
    const int* __restrict__ bsum, int* __restrict__ boffs, int NB) {
    __shared__ int sh[SCAN_BS];
    int t = threadIdx.x;
    int v = (t < NB) ? bsum[t] : 0;
    sh[t] = v;
    __syncthreads();
    for (int o = 1; o < SCAN_BS; o <<= 1) {
        int u = (t >= o) ? sh[t - o] : 0;
        __syncthreads();
        sh[t] += u;
        __syncthreads();
    }
    if (t < NB) boffs[t] = sh[t] - v;
}

__global__ void k_add_offsets(int* __restrict__ rowptr,
                              const int* __restrict__ boffs, int N, int E) {
    int i = blockIdx.x * blockDim.x + threadIdx.x;
    if (i < N) rowptr[i] += boffs[i >> 10];
    if (i == 0) rowptr[N] = E;
}

// ---- key scatter (atomic-free: pos = rowptr[obj] + rank[e]) ----------------
__global__ void k_key(const int* __restrict__ edges, int E,
                      const int* __restrict__ rowptr,
                      const int* __restrict__ rank,
                      unsigned int* __restrict__ key) {
    int e = blockIdx.x * blockDim.x + threadIdx.x;
    if (e >= E) return;
    const int* ed = edges + (size_t)e * 6;
    int r_idx = ed[0], rel = ed[2], sub = ed[4], obj = ed[5];
    int pos = rowptr[obj] + rank[e];
    key[pos] = (unsigned int)sub | ((unsigned int)(rel * 8 + r_idx) << 18);
}

// ---- FUSED alpha + aggregation, 2 edges per wave ---------------------------
// Lanes 0-31 = edge j, lanes 32-63 = edge j+1; each lane owns 2 features
// (float2). One gather instruction per table serves BOTH edges; 5-shuffle
// reduce (within 32-halves) and one sigmoid cover both edges. 2-deep
// pipeline. Zero feature atomics; one 256 B store per node.
__global__ __launch_bounds__(256) void k_agg(
    const int* __restrict__ rowptr,
    const unsigned int* __restrict__ key,
    const float* __restrict__ hproj,
    const float* __restrict__ ct,
    const float* __restrict__ hidden,
    const float* __restrict__ rela,
    const float* __restrict__ wa,
    const float* __restrict__ wab_p,
    float* __restrict__ agg, int N) {
    int lane = threadIdx.x & 63;
    int half = lane >> 5;
    int li   = lane & 31;
    int w = (int)((blockIdx.x * blockDim.x + threadIdx.x) >> 6);
    if (w >= N) return;
    int n = __builtin_amdgcn_readfirstlane(w);
    int s = rowptr[n], e = rowptr[n + 1];
    const float2* hproj2  = (const float2*)hproj;
    const float2* ct2     = (const float2*)ct;
    const float2* hidden2 = (const float2*)hidden;
    const float2* rela2   = (const float2*)rela;
    float2 wav = ((const float2*)wa)[li];
    float wab = wab_p[0];
    float2 acc = {0.f, 0.f};

    if (s < e) {
        // prologue: load pair at j=s
        int j1c = min(s + 1, e - 1);
        unsigned int ka = key[s], kb = key[j1c];      // uniform s_loads
        unsigned int kk = half ? kb : ka;
        float vld = (half == 0 || s + 1 < e) ? 1.f : 0.f;
        int sub = (int)(kk & 0x3FFFFu);
        int cr  = (int)(kk >> 18);
        float2 hp = hproj2[(size_t)sub * 32 + li];
        float2 cv = ct2[(size_t)cr * 32 + li];
        float2 hd = hidden2[(size_t)sub * 32 + li];
        float2 rl = rela2[(size_t)(cr >> 3) * 32 + li];

        for (int j = s + 2; j < e; j += 2) {
            // prefetch next pair
            int j1n = min(j + 1, e - 1);
            unsigned int ka1 = key[j], kb1 = key[j1n];
            unsigned int kk1 = half ? kb1 : ka1;
            float vld1 = (half == 0 || j + 1 < e) ? 1.f : 0.f;
            int sub1 = (int)(kk1 & 0x3FFFFu);
            int cr1  = (int)(kk1 >> 18);
            float2 hp1 = hproj2[(size_t)sub1 * 32 + li];
            float2 cv1 = ct2[(size_t)cr1 * 32 + li];
            float2 hd1 = hidden2[(size_t)sub1 * 32 + li];
            float2 rl1 = rela2[(size_t)(cr1 >> 3) * 32 + li];
            // consume current pair
            float t = fmaxf(hp.x + cv.x, 0.f) * wav.x
                    + fmaxf(hp.y + cv.y, 0.f) * wav.y;
#pragma unroll
            for (int o = 16; o; o >>= 1) t += __shfl_xor(t, o, 64);
            float am = vld / (1.f + __expf(-(t + wab)));
            acc.x += am * (hd.x + rl.x);
            acc.y += am * (hd.y + rl.y);
            hp = hp1; cv = cv1; hd = hd1; rl = rl1; vld = vld1;
        }
        float t = fmaxf(hp.x + cv.x, 0.f) * wav.x
                + fmaxf(hp.y + cv.y, 0.f) * wav.y;
#pragma unroll
        for (int o = 16; o; o >>= 1) t += __shfl_xor(t, o, 64);
        float am = vld / (1.f + __expf(-(t + wab)));
        acc.x += am * (hd.x + rl.x);
        acc.y += am * (hd.y + rl.y);
    }
    // combine the two halves, store by lanes 0-31 (256 B coalesced)
    acc.x += __shfl_xor(acc.x, 32, 64);
    acc.y += __shfl_xor(acc.y, 32, 64);
    if (half == 0) ((float2*)agg)[(size_t)n * 32 + li] = acc;
}

extern "C" void kernel_launch(void* const* d_in, const int* in_sizes, int n_in,
                              void* d_out, int out_size, void* d_ws, size_t ws_size,
                              hipStream_t stream) {
    const int* q_rel    = (const int*)d_in[1];
    const float* hidden = (const float*)d_in[2];
    const int* edges    = (const int*)d_in[3];
    const float* rela   = (const float*)d_in[7];
    const float* Ws     = (const float*)d_in[8];
    const float* Wr     = (const float*)d_in[9];
    const float* WqrW   = (const float*)d_in[10];
    const float* Wqrb   = (const float*)d_in[11];
    const float* waW    = (const float*)d_in[12];
    const float* wab    = (const float*)d_in[13];
    const float* Wh     = (const float*)d_in[14];

    int E = in_sizes[3] / 6;            // 1,000,000
    int n_node = in_sizes[4] / 2;       // 200,000
    int n_rel_tot = in_sizes[7] / 64;   // 401
    int B = in_sizes[0];                // 8 (k_ct/k_key assume <= 8)
    int NB = (n_node + 1023) / 1024;    // scan blocks (196 <= 256)

    float* agg = (float*)d_out;                          // n_node*64
    char* w = (char*)d_ws;
    float* hproj = (float*)w;                  w += (size_t)n_node * 64 * 4;
    float* ct    = (float*)w;                  w += (size_t)n_rel_tot * 8 * 64 * 4;
    unsigned int* key = (unsigned int*)w;      w += (size_t)E * 4;
    int* rank   = (int*)w;                     w += (size_t)E * 4;
    int* deg    = (int*)w;                     w += (size_t)n_node * 4;
    int* rowptr = (int*)w;                     w += (size_t)(n_node + 1) * 4;
    int* bsum   = (int*)w;                     w += (size_t)NB * 4;
    int* boffs  = (int*)w;                     w += (size_t)NB * 4;

    // node projection + combined attention table
    rowproj64<<<n_node / 64, 256, 0, stream>>>(hidden, Ws, hproj, n_node);
    k_ct<<<n_rel_tot, 64, 0, stream>>>(rela, q_rel, Wr, WqrW, Wqrb, ct, B);

    // CSR build (rank captured during count; no cursor atomics later)
    hipMemsetAsync(deg, 0, (size_t)n_node * 4, stream);
    k_count<<<(E + 255) / 256, 256, 0, stream>>>(edges, E, deg, rank);
    k_scan_block<<<NB, SCAN_BS, 0, stream>>>(deg, n_node, rowptr, bsum);
    k_scan_partials<<<1, SCAN_BS, 0, stream>>>(bsum, boffs, NB);
    k_add_offsets<<<(n_node + 255) / 256, 256, 0, stream>>>(rowptr, boffs,
                                                            n_node, E);

    // key scatter (atomic-free), fused alpha+aggregate, out-projection
    k_key<<<(E + 255) / 256, 256, 0, stream>>>(edges, E, rowptr, rank, key);
    k_agg<<<(n_node * 64 + 255) / 256, 256, 0, stream>>>(
        rowptr, key, hproj, ct, hidden, rela, waW, wab, agg, n_node);
    rowproj64<<<n_node / 64, 256, 0, stream>>>(agg, Wh, agg, n_node);
}